// Round 1
// baseline (835.968 us; speedup 1.0000x reference)
//
#include <hip/hip_runtime.h>

typedef _Float16 half8 __attribute__((ext_vector_type(8)));
typedef float f32x4 __attribute__((ext_vector_type(4)));

#define LDSROW 136  // halfs per padded LDS row: 128 + 8 pad -> 272 B, 16B-aligned

// One wave = 64 atoms x all 256 (=4 elements x 64 hidden) columns.
// A (x tile) direct global->reg fp16; B (W1) from LDS fp16 transposed; C fp32 MFMA acc.
__global__ __launch_bounds__(256, 2)
void elemental_atomwise_kernel(const float* __restrict__ x,
                               const int* __restrict__ zidx,
                               const int* __restrict__ idx_m,
                               const float* __restrict__ W1,
                               const float* __restrict__ b1,
                               const float* __restrict__ W2,
                               const float* __restrict__ b2,
                               float* __restrict__ y,
                               int N) {
  extern __shared__ _Float16 w1t[];  // [256 rows (e*64+h)][LDSROW] of k=d

  // ---- stage W1 fp32 [4][128][64] -> LDS fp16 transposed [n][d] (once per block) ----
#pragma unroll
  for (int it = 0; it < 32; ++it) {
    int idx4 = threadIdx.x + it * 256;      // float4 index, 0..8191
    f32x4 v = ((const f32x4*)W1)[idx4];
    int lin = idx4 << 2;                    // flat element index e*8192 + d*64 + h
    int e = lin >> 13;
    int d = (lin >> 6) & 127;
    int h = lin & 63;
    int n = e * 64 + h;
#pragma unroll
    for (int j = 0; j < 4; ++j)
      w1t[(n + j) * LDSROW + d] = (_Float16)v[j];
  }
  __syncthreads();

  const int lane = threadIdx.x & 63;
  const int wave = threadIdx.x >> 6;
  const int c = lane & 15;  // 16-wide index (M rows for A, N cols for B/C)
  const int q = lane >> 4;  // quad
  const long tile = (long)blockIdx.x * 4 + wave;
  const long base = tile * 64;
  if (base >= N) return;

  // per-atom metadata, lane <-> atom within tile
  int ameta = (base + lane < N) ? (int)(base + lane) : (N - 1);
  const int zvec = zidx[ameta];
  const int ivec = idx_m[ameta];

  // ---- A fragments: lane holds row m = mt*16 + c, k = q*8..q*8+7 (per kt block) ----
  half8 af[4][4];
#pragma unroll
  for (int mt = 0; mt < 4; ++mt) {
    long row = base + mt * 16 + c;
    if (row >= N) row = N - 1;
    const f32x4* rp = (const f32x4*)(x + row * 128);
#pragma unroll
    for (int kt = 0; kt < 4; ++kt) {
      f32x4 u0 = rp[kt * 8 + q * 2];
      f32x4 u1 = rp[kt * 8 + q * 2 + 1];
      half8 a;
      a[0] = (_Float16)u0[0]; a[1] = (_Float16)u0[1];
      a[2] = (_Float16)u0[2]; a[3] = (_Float16)u0[3];
      a[4] = (_Float16)u1[0]; a[5] = (_Float16)u1[1];
      a[6] = (_Float16)u1[2]; a[7] = (_Float16)u1[3];
      af[mt][kt] = a;
    }
  }

#pragma unroll
  for (int e = 0; e < 4; ++e) {
    f32x4 acc[4][4];
#pragma unroll
    for (int mt = 0; mt < 4; ++mt)
#pragma unroll
      for (int nt = 0; nt < 4; ++nt)
        acc[mt][nt] = (f32x4){0.f, 0.f, 0.f, 0.f};

#pragma unroll
    for (int kt = 0; kt < 4; ++kt) {
#pragma unroll
      for (int nt = 0; nt < 4; ++nt) {
        // B frag: lane holds col n = nt*16 + c, k = kt*32 + q*8 + j  (contiguous in LDS row)
        half8 bf = *(const half8*)&w1t[(e * 64 + nt * 16 + c) * LDSROW + kt * 32 + q * 8];
#pragma unroll
        for (int mt = 0; mt < 4; ++mt)
          acc[mt][nt] = __builtin_amdgcn_mfma_f32_16x16x32_f16(af[mt][kt], bf, acc[mt][nt], 0, 0, 0);
      }
    }

    // ---- epilogue: bias + shifted softplus + layer-2 dot + lane reduce + atomic ----
    float b1v[4], w2v[4];
#pragma unroll
    for (int nt = 0; nt < 4; ++nt) {
      b1v[nt] = b1[e * 64 + nt * 16 + c];
      w2v[nt] = W2[e * 64 + nt * 16 + c];
    }
    const float b2e = b2[e];
#pragma unroll
    for (int mt = 0; mt < 4; ++mt) {
#pragma unroll
      for (int i = 0; i < 4; ++i) {
        // C layout: col = c, row = q*4 + i  -> atom = base + mt*16 + q*4 + i
        float s = 0.0f;
#pragma unroll
        for (int nt = 0; nt < 4; ++nt) {
          float t = acc[mt][nt][i] + b1v[nt];
          float hsp = __logf(1.0f + __expf(t)) - 0.69314718056f;  // ssp
          s = fmaf(hsp, w2v[nt], s);
        }
        // reduce over the 16 c-lanes (same atom)
        s += __shfl_xor(s, 1);
        s += __shfl_xor(s, 2);
        s += __shfl_xor(s, 4);
        s += __shfl_xor(s, 8);
        int mloc = mt * 16 + q * 4 + i;
        int zm = __shfl(zvec, mloc);
        int im = __shfl(ivec, mloc);
        if (c == 0 && zm == e && base + mloc < N)
          atomicAdd(&y[im], s + b2e);
      }
    }
  }
}

extern "C" void kernel_launch(void* const* d_in, const int* in_sizes, int n_in,
                              void* d_out, int out_size, void* d_ws, size_t ws_size,
                              hipStream_t stream) {
  const float* x = (const float*)d_in[0];
  const int* zidx = (const int*)d_in[1];
  const int* idx_m = (const int*)d_in[2];
  const float* W1 = (const float*)d_in[3];
  const float* b1 = (const float*)d_in[4];
  const float* W2 = (const float*)d_in[5];
  const float* b2 = (const float*)d_in[6];
  float* y = (float*)d_out;

  const int N = in_sizes[0] / 128;

  // y is accumulated with atomics: zero it first (d_out is poisoned 0xAA)
  hipMemsetAsync(d_out, 0, (size_t)out_size * sizeof(float), stream);

  const int tiles = (N + 63) / 64;
  const int blocks = (tiles + 3) / 4;
  const size_t lds_bytes = 256 * LDSROW * sizeof(_Float16);  // 69632 B

  elemental_atomwise_kernel<<<blocks, 256, lds_bytes, stream>>>(
      x, zidx, idx_m, W1, b1, W2, b2, y, N);
}